// Round 2
// baseline (215.832 us; speedup 1.0000x reference)
//
#include <hip/hip_runtime.h>
#include <hip/hip_bf16.h>

typedef __attribute__((ext_vector_type(8))) __bf16 bf16x8;
typedef __attribute__((ext_vector_type(8))) short  s16x8;
typedef __attribute__((ext_vector_type(4))) short  s16x4;
typedef __attribute__((ext_vector_type(4))) float  f32x4;

#define HW2 1024   // h*w
#define CDIM 512   // channels

static __device__ __forceinline__ unsigned short f2b(float f) {
  __hip_bfloat16 h = __float2bfloat16(f);
  return __builtin_bit_cast(unsigned short, h);
}

static __device__ __forceinline__ f32x4 mfma16(s16x8 a, s16x8 b, f32x4 c) {
  return __builtin_amdgcn_mfma_f32_16x16x32_bf16(
      __builtin_bit_cast(bf16x8, a), __builtin_bit_cast(bf16x8, b), c, 0, 0, 0);
}

// ---------------- fused prep ----------------
__global__ __launch_bounds__(256) void k_prep(
    const float* __restrict__ w_qkv, const float* __restrict__ w_ht,
    const float* __restrict__ table, const int* __restrict__ idx,
    unsigned short* __restrict__ Wtq, unsigned short* __restrict__ Wtk,
    unsigned short* __restrict__ Wtv, unsigned short* __restrict__ WhtT,
    float* __restrict__ pe) {
  int blk = blockIdx.x;
  if (blk < 16) {
    int i = blk * 256 + threadIdx.x;           // 4096
    int c = i >> 6, k = i & 63;
    const float* src = w_qkv + k * 192 + 3 * c;
    Wtq[i] = f2b(src[0] * 0.125f);
    Wtk[i] = f2b(src[1]);
    Wtv[i] = f2b(src[2]);
  } else if (blk < 1040) {
    int i = (blk - 16) * 256 + threadIdx.x;    // 262144
    int c = i >> 9, k = i & 511;
    WhtT[i] = f2b(w_ht[k * 512 + c]);
  } else {
    int i = (blk - 1040) * 256 + threadIdx.x;  // 262144 threads x 4
    #pragma unroll
    for (int j = 0; j < 4; ++j) {
      int p = i + j * 262144;
      __builtin_nontemporal_store(table[idx[p]], pe + p);
    }
  }
}

// ---------------- QKV projection ----------------
// Per wg: one bm, 64 pixels. 4 waves x 16 rows. K=64, N=192 (12 col-tiles).
// Q/K computed with SWAPPED mfma operands (D col = pixel) so each lane holds
// 4 consecutive channels of one pixel -> packed b64 stores, no LDS at all.
// V keeps original order (D row = pixel) -> lane holds 4 consecutive pixels
// of one channel -> packed b64 stores directly in transposed [dh][p] layout.
__global__ __launch_bounds__(256) void k_qkv(const float* __restrict__ x,
    const float* __restrict__ b_qkv,
    const unsigned short* __restrict__ Wtq, const unsigned short* __restrict__ Wtk,
    const unsigned short* __restrict__ Wtv,
    unsigned short* __restrict__ Qb, unsigned short* __restrict__ Kb,
    unsigned short* __restrict__ Vt) {
  int bm = blockIdx.x >> 4;
  int pt = blockIdx.x & 15;
  int wid = threadIdx.x >> 6, lane = threadIdx.x & 63;
  int l15 = lane & 15, lg = lane >> 4;
  int b = bm >> 3, m = bm & 7;
  int pbase = pt * 64 + wid * 16;

  // x fragment (f32 -> bf16); serves as both A- and B-operand (same layout).
  int pA = pbase + l15;
  const float* xp = x + (size_t)(b * HW2 + pA) * CDIM + m * 64 + lg * 8;
  f32x4 xv0 = *(const f32x4*)(xp);
  f32x4 xv1 = *(const f32x4*)(xp + 4);
  f32x4 xv2 = *(const f32x4*)(xp + 32);
  f32x4 xv3 = *(const f32x4*)(xp + 36);
  s16x8 a0, a1;
  #pragma unroll
  for (int j = 0; j < 4; ++j) {
    a0[j]     = (short)f2b(xv0[j]);
    a0[4 + j] = (short)f2b(xv1[j]);
    a1[j]     = (short)f2b(xv2[j]);
    a1[4 + j] = (short)f2b(xv3[j]);
  }

  f32x4 acc[12];
  #pragma unroll
  for (int ct = 0; ct < 12; ++ct) acc[ct] = (f32x4){0.f, 0.f, 0.f, 0.f};

  #pragma unroll
  for (int ct = 0; ct < 12; ++ct) {
    const unsigned short* W = (ct < 4) ? Wtq : (ct < 8 ? Wtk : Wtv);
    int c = (ct & 3) * 16 + l15;
    const unsigned short* wp = W + c * 64 + lg * 8;
    s16x8 b0 = *(const s16x8*)(wp);
    s16x8 b1 = *(const s16x8*)(wp + 32);
    if (ct < 8) {            // Q, K: swapped -> D[row=c][col=p]
      acc[ct] = mfma16(b0, a0, acc[ct]);
      acc[ct] = mfma16(b1, a1, acc[ct]);
    } else {                 // V: original -> D[row=p][col=c]
      acc[ct] = mfma16(a0, b0, acc[ct]);
      acc[ct] = mfma16(a1, b1, acc[ct]);
    }
  }

  // Q/K: lane -> pixel pbase+l15, channels c0..c0+3 (packed b64)
  #pragma unroll
  for (int ct = 0; ct < 8; ++ct) {
    int s = ct >> 2;
    int c0 = (ct & 3) * 16 + lg * 4;
    unsigned short* D = (s == 0) ? Qb : Kb;
    s16x4 pk;
    #pragma unroll
    for (int i = 0; i < 4; ++i) {
      float bias = b_qkv[3 * (c0 + i) + s];
      if (s == 0) bias *= 0.125f;
      pk[i] = (short)f2b(acc[ct][i] + bias);
    }
    *(s16x4*)(D + (size_t)(bm * HW2 + pbase + l15) * 64 + c0) = pk;
  }
  // V: lane -> channel c, pixels pbase+lg*4.. (packed b64, transposed layout)
  #pragma unroll
  for (int ct = 8; ct < 12; ++ct) {
    int c = (ct & 3) * 16 + l15;
    float bias = b_qkv[3 * c + 2];
    s16x4 pk;
    #pragma unroll
    for (int i = 0; i < 4; ++i) pk[i] = (short)f2b(acc[ct][i] + bias);
    *(s16x4*)(Vt + ((size_t)bm * 64 + c) * HW2 + pbase + lg * 4) = pk;
  }
}

// ---------------- fused attention ----------------
// Swapped QK^T: acc = mfma(K, Q) -> D[row=att-col][col=q-row]. Each lane owns
// one q-row (l15) and 64 att-cols -> scalar per-lane softmax state, f32x4 att
// stores, packed b64 P writes, packed b64 O stores (no staging tile).
// XCD-aware decode: all 64 q-tiles of a bm land on one XCD -> K/V L2-resident.
__global__ __launch_bounds__(256, 4) void k_attn(
    const unsigned short* __restrict__ Qb, const unsigned short* __restrict__ Kb,
    const unsigned short* __restrict__ Vt, const float* __restrict__ ptab,
    float* __restrict__ att, unsigned short* __restrict__ O) {
  int r8 = blockIdx.x & 7;
  int kk = blockIdx.x >> 3;
  int qt = kk & 63;
  int bm = ((kk >> 6) << 3) | r8;
  int wid = threadIdx.x >> 6, lane = threadIdx.x & 63;
  int l15 = lane & 15, lg = lane >> 4;

  __shared__ unsigned short P[16][1032];   // padded: row stride 2064 B
  __shared__ float redm[4][16];
  __shared__ float reds[4][16];

  // Q fragment (B-operand: col = q-row)
  const unsigned short* qp = Qb + (size_t)(bm * HW2 + qt * 16 + l15) * 64 + lg * 8;
  s16x8 qa0 = *(const s16x8*)qp;
  s16x8 qa1 = *(const s16x8*)(qp + 32);

  // S^T = K Q over this wave's 256 att-cols
  f32x4 acc[16];
  const unsigned short* kbase = Kb + (size_t)bm * HW2 * 64;
  #pragma unroll
  for (int ct = 0; ct < 16; ++ct) {
    int col = wid * 256 + ct * 16 + l15;
    const unsigned short* kp = kbase + (size_t)col * 64 + lg * 8;
    s16x8 kb0 = *(const s16x8*)kp;
    s16x8 kb1 = *(const s16x8*)(kp + 32);
    f32x4 a = (f32x4){0.f, 0.f, 0.f, 0.f};
    a = mfma16(kb0, qa0, a);
    a = mfma16(kb1, qa1, a);
    acc[ct] = a;
  }

  // + pos bias from table (forward dwordx4 gathers), per-lane row max.
  // idx(qr,col) = 63*(col>>5) + (col&31) + 1984 - 63*(qr>>5) - (qr&31);
  // qr = qt*16 + l15 (one row per lane).
  int cb = 1984 - 63 * (qt >> 1) - ((qt & 1) << 4) - l15;
  float pm = -1e30f;
  #pragma unroll
  for (int ct = 0; ct < 16; ++ct) {
    int c0 = wid * 256 + ct * 16 + lg * 4;
    int t0 = 63 * (c0 >> 5) + (c0 & 31) + cb;
    f32x4 pv;
    __builtin_memcpy(&pv, ptab + t0, 16);
    #pragma unroll
    for (int i = 0; i < 4; ++i) {
      float v = acc[ct][i] + pv[i];
      acc[ct][i] = v;
      pm = fmaxf(pm, v);
    }
  }
  pm = fmaxf(pm, __shfl_xor(pm, 16));
  pm = fmaxf(pm, __shfl_xor(pm, 32));
  if (lane < 16) redm[wid][l15] = pm;
  __syncthreads();
  float mrow = fmaxf(fmaxf(redm[0][l15], redm[1][l15]),
                     fmaxf(redm[2][l15], redm[3][l15]));

  // exp + per-lane sum
  float ps = 0.f;
  #pragma unroll
  for (int ct = 0; ct < 16; ++ct) {
    #pragma unroll
    for (int i = 0; i < 4; ++i) {
      float e = __expf(acc[ct][i] - mrow);
      acc[ct][i] = e;
      ps += e;
    }
  }
  ps += __shfl_xor(ps, 16);
  ps += __shfl_xor(ps, 32);
  if (lane < 16) reds[wid][l15] = ps;
  __syncthreads();
  float inv = 1.0f / (reds[0][l15] + reds[1][l15] + reds[2][l15] + reds[3][l15]);

  // att (f32x4, nontemporal) + P (packed b64) -- lane owns row qt*16+l15
  float* abase = att + (size_t)(bm * HW2 + qt * 16 + l15) * HW2;
  #pragma unroll
  for (int ct = 0; ct < 16; ++ct) {
    int c0 = wid * 256 + ct * 16 + lg * 4;
    f32x4 vv;
    #pragma unroll
    for (int i = 0; i < 4; ++i) vv[i] = acc[ct][i] * inv;
    __builtin_nontemporal_store(vv, (f32x4*)(abase + c0));
    s16x4 pk;
    #pragma unroll
    for (int i = 0; i < 4; ++i) pk[i] = (short)f2b(vv[i]);
    *(s16x4*)&P[l15][c0] = pk;
  }
  __syncthreads();

  // o = P @ V, swapped: mfma(V, P) -> D[row=dh][col=q-row] -> packed b64 O
  f32x4 o = (f32x4){0.f, 0.f, 0.f, 0.f};
  const unsigned short* vbase = Vt + (size_t)(bm * 64 + wid * 16 + l15) * HW2;
  #pragma unroll
  for (int kt = 0; kt < 32; ++kt) {
    s16x8 vb = *(const s16x8*)(vbase + kt * 32 + lg * 8);
    s16x8 pa = *(const s16x8*)&P[l15][kt * 32 + lg * 8];
    o = mfma16(vb, pa, o);
  }
  s16x4 ok;
  #pragma unroll
  for (int i = 0; i < 4; ++i) ok[i] = (short)f2b(o[i]);
  *(s16x4*)(O + (size_t)(bm * HW2 + qt * 16 + l15) * 64 + wid * 16 + lg * 4) = ok;
}

// ---------------- head transform: out = gather(O) @ w_ht + b_ht ----------------
// Swapped operands -> D col = pixel row -> f32x4 nontemporal out stores.
__global__ __launch_bounds__(256) void k_ht(
    const unsigned short* __restrict__ O, const unsigned short* __restrict__ WhtT,
    const float* __restrict__ b_ht, float* __restrict__ out) {
  int rt = blockIdx.x >> 1;
  int ch = blockIdx.x & 1;
  int wid = threadIdx.x >> 6, lane = threadIdx.x & 63;
  int wr = wid >> 1, wc = wid & 1;
  int l15 = lane & 15, lg = lane >> 4;
  int b = (rt * 32) >> 10;
  int p0 = (rt * 32) & 1023;

  __shared__ unsigned short A[32][520];   // padded: row stride 1040 B

  int t = threadIdx.x;
  #pragma unroll
  for (int j = 0; j < 8; ++j) {
    int idx = t * 8 + j * 2048;          // [0, 16384)
    int row = idx >> 9;
    int k0 = idx & 511;
    int m = k0 >> 6, kk = k0 & 63;
    const unsigned short* src = O + (size_t)((b * 8 + m) * HW2 + p0 + row) * 64 + kk;
    *(s16x8*)&A[row][k0] = *(const s16x8*)src;
  }
  __syncthreads();

  f32x4 acc[8];
  #pragma unroll
  for (int ct = 0; ct < 8; ++ct) acc[ct] = (f32x4){0.f, 0.f, 0.f, 0.f};

  #pragma unroll
  for (int kt = 0; kt < 16; ++kt) {
    s16x8 a = *(const s16x8*)&A[wr * 16 + l15][kt * 32 + lg * 8];
    #pragma unroll
    for (int ct = 0; ct < 8; ++ct) {
      int col = ch * 256 + wc * 128 + ct * 16 + l15;
      s16x8 bf = *(const s16x8*)(WhtT + (size_t)col * 512 + kt * 32 + lg * 8);
      acc[ct] = mfma16(bf, a, acc[ct]);   // swapped: D[row=col][col=pixel]
    }
  }

  int rp = rt * 32 + wr * 16 + l15;
  #pragma unroll
  for (int ct = 0; ct < 8; ++ct) {
    int c0 = ch * 256 + wc * 128 + ct * 16 + lg * 4;
    f32x4 bb = *(const f32x4*)(b_ht + c0);
    f32x4 ov;
    #pragma unroll
    for (int i = 0; i < 4; ++i) ov[i] = acc[ct][i] + bb[i];
    __builtin_nontemporal_store(ov, (f32x4*)(out + (size_t)rp * 512 + c0));
  }
}

// ---------------- launcher ----------------
extern "C" void kernel_launch(void* const* d_in, const int* in_sizes, int n_in,
                              void* d_out, int out_size, void* d_ws, size_t ws_size,
                              hipStream_t stream) {
  const float* x         = (const float*)d_in[0];
  const float* w_qkv     = (const float*)d_in[1];
  const float* b_qkv     = (const float*)d_in[2];
  const float* w_ht      = (const float*)d_in[3];
  const float* b_ht      = (const float*)d_in[4];
  const float* pos_table = (const float*)d_in[5];
  const int*   pos_idx   = (const int*)d_in[6];

  float* out = (float*)d_out;                  // 4,194,304
  float* att = out + 4194304;                  // 67,108,864
  float* pe  = att + 67108864;                 // 1,048,576

  char* ws = (char*)d_ws;
  unsigned short* Qb   = (unsigned short*)(ws);
  unsigned short* Kb   = (unsigned short*)(ws + (8u  << 20));
  unsigned short* Vt   = (unsigned short*)(ws + (16u << 20));
  unsigned short* O    = (unsigned short*)(ws + (24u << 20));
  unsigned short* Wtq  = (unsigned short*)(ws + (32u << 20));
  unsigned short* Wtk  = Wtq + 4096;
  unsigned short* Wtv  = Wtk + 4096;
  unsigned short* WhtT = (unsigned short*)(ws + (32u << 20) + 65536);

  k_prep<<<2064, 256, 0, stream>>>(w_qkv, w_ht, pos_table, pos_idx,
                                   Wtq, Wtk, Wtv, WhtT, pe);
  k_qkv <<<1024, 256, 0, stream>>>(x, b_qkv, Wtq, Wtk, Wtv, Qb, Kb, Vt);
  k_attn<<<4096, 256, 0, stream>>>(Qb, Kb, Vt, pos_table, att, O);
  k_ht  <<<512,  256, 0, stream>>>(O, WhtT, b_ht, out);
}

// Round 4
// 202.761 us; speedup vs baseline: 1.0645x; 1.0645x over previous
//
#include <hip/hip_runtime.h>
#include <hip/hip_bf16.h>

typedef __attribute__((ext_vector_type(8))) __bf16 bf16x8;
typedef __attribute__((ext_vector_type(8))) short  s16x8;
typedef __attribute__((ext_vector_type(4))) short  s16x4;
typedef __attribute__((ext_vector_type(4))) float  f32x4;

#define HW2 1024   // h*w
#define CDIM 512   // channels

static __device__ __forceinline__ unsigned short f2b(float f) {
  __hip_bfloat16 h = __float2bfloat16(f);
  return __builtin_bit_cast(unsigned short, h);
}

static __device__ __forceinline__ f32x4 mfma16(s16x8 a, s16x8 b, f32x4 c) {
  return __builtin_amdgcn_mfma_f32_16x16x32_bf16(
      __builtin_bit_cast(bf16x8, a), __builtin_bit_cast(bf16x8, b), c, 0, 0, 0);
}

// ---------------- fused prep ----------------
__global__ __launch_bounds__(256) void k_prep(
    const float* __restrict__ w_qkv, const float* __restrict__ w_ht,
    const float* __restrict__ table, const int* __restrict__ idx,
    unsigned short* __restrict__ Wtq, unsigned short* __restrict__ Wtk,
    unsigned short* __restrict__ Wtv, unsigned short* __restrict__ WhtT,
    float* __restrict__ pe) {
  int blk = blockIdx.x;
  if (blk < 16) {
    int i = blk * 256 + threadIdx.x;           // 4096
    int c = i >> 6, k = i & 63;
    const float* src = w_qkv + k * 192 + 3 * c;
    Wtq[i] = f2b(src[0] * 0.125f);
    Wtk[i] = f2b(src[1]);
    Wtv[i] = f2b(src[2]);
  } else if (blk < 1040) {
    int i = (blk - 16) * 256 + threadIdx.x;    // 262144
    int c = i >> 9, k = i & 511;
    WhtT[i] = f2b(w_ht[k * 512 + c]);
  } else {
    int i = (blk - 1040) * 256 + threadIdx.x;  // 262144 threads x 4
    #pragma unroll
    for (int j = 0; j < 4; ++j) {
      int p = i + j * 262144;
      __builtin_nontemporal_store(table[idx[p]], pe + p);
    }
  }
}

// ---------------- QKV projection ----------------
// Per wg: one bm, 64 pixels. 4 waves x 16 rows. K=64, N=192 (12 col-tiles).
// Q/K with swapped mfma operands (D col = pixel) -> packed b64 stores;
// V original order -> packed b64 stores directly in transposed [dh][p] layout.
__global__ __launch_bounds__(256) void k_qkv(const float* __restrict__ x,
    const float* __restrict__ b_qkv,
    const unsigned short* __restrict__ Wtq, const unsigned short* __restrict__ Wtk,
    const unsigned short* __restrict__ Wtv,
    unsigned short* __restrict__ Qb, unsigned short* __restrict__ Kb,
    unsigned short* __restrict__ Vt) {
  int bm = blockIdx.x >> 4;
  int pt = blockIdx.x & 15;
  int wid = threadIdx.x >> 6, lane = threadIdx.x & 63;
  int l15 = lane & 15, lg = lane >> 4;
  int b = bm >> 3, m = bm & 7;
  int pbase = pt * 64 + wid * 16;

  int pA = pbase + l15;
  const float* xp = x + (size_t)(b * HW2 + pA) * CDIM + m * 64 + lg * 8;
  f32x4 xv0 = *(const f32x4*)(xp);
  f32x4 xv1 = *(const f32x4*)(xp + 4);
  f32x4 xv2 = *(const f32x4*)(xp + 32);
  f32x4 xv3 = *(const f32x4*)(xp + 36);
  s16x8 a0, a1;
  #pragma unroll
  for (int j = 0; j < 4; ++j) {
    a0[j]     = (short)f2b(xv0[j]);
    a0[4 + j] = (short)f2b(xv1[j]);
    a1[j]     = (short)f2b(xv2[j]);
    a1[4 + j] = (short)f2b(xv3[j]);
  }

  f32x4 acc[12];
  #pragma unroll
  for (int ct = 0; ct < 12; ++ct) acc[ct] = (f32x4){0.f, 0.f, 0.f, 0.f};

  #pragma unroll
  for (int ct = 0; ct < 12; ++ct) {
    const unsigned short* W = (ct < 4) ? Wtq : (ct < 8 ? Wtk : Wtv);
    int c = (ct & 3) * 16 + l15;
    const unsigned short* wp = W + c * 64 + lg * 8;
    s16x8 b0 = *(const s16x8*)(wp);
    s16x8 b1 = *(const s16x8*)(wp + 32);
    if (ct < 8) {            // Q, K: swapped -> D[row=c][col=p]
      acc[ct] = mfma16(b0, a0, acc[ct]);
      acc[ct] = mfma16(b1, a1, acc[ct]);
    } else {                 // V: original -> D[row=p][col=c]
      acc[ct] = mfma16(a0, b0, acc[ct]);
      acc[ct] = mfma16(a1, b1, acc[ct]);
    }
  }

  #pragma unroll
  for (int ct = 0; ct < 8; ++ct) {
    int s = ct >> 2;
    int c0 = (ct & 3) * 16 + lg * 4;
    unsigned short* D = (s == 0) ? Qb : Kb;
    s16x4 pk;
    #pragma unroll
    for (int i = 0; i < 4; ++i) {
      float bias = b_qkv[3 * (c0 + i) + s];
      if (s == 0) bias *= 0.125f;
      pk[i] = (short)f2b(acc[ct][i] + bias);
    }
    *(s16x4*)(D + (size_t)(bm * HW2 + pbase + l15) * 64 + c0) = pk;
  }
  #pragma unroll
  for (int ct = 8; ct < 12; ++ct) {
    int c = (ct & 3) * 16 + l15;
    float bias = b_qkv[3 * c + 2];
    s16x4 pk;
    #pragma unroll
    for (int i = 0; i < 4; ++i) pk[i] = (short)f2b(acc[ct][i] + bias);
    *(s16x4*)(Vt + ((size_t)bm * 64 + c) * HW2 + pbase + lg * 4) = pk;
  }
}

// ---------------- fused attention ----------------
// Swapped QK^T: acc = mfma(K, Q) -> lane owns one q-row (l15), 64 att-cols.
// att stores bounced through XOR-swizzled per-wave LDS staging (explicit
// barriers) -> 256B full-line segments. XCD-aware decode keeps K/V L2-local.
__global__ __launch_bounds__(256, 3) void k_attn(
    const unsigned short* __restrict__ Qb, const unsigned short* __restrict__ Kb,
    const unsigned short* __restrict__ Vt, const float* __restrict__ ptab,
    float* __restrict__ att, unsigned short* __restrict__ O) {
  int r8 = blockIdx.x & 7;
  int kk = blockIdx.x >> 3;
  int qt = kk & 63;
  int bm = ((kk >> 6) << 3) | r8;
  int wid = threadIdx.x >> 6, lane = threadIdx.x & 63;
  int l15 = lane & 15, lg = lane >> 4;

  __shared__ unsigned short P[16][1032];           // padded: row stride 2064 B
  __shared__ __align__(16) float stg[4][16][64];   // per-wave, XOR-swizzled
  __shared__ float redm[4][16];
  __shared__ float reds[4][16];

  // Q fragment (B-operand: col = q-row)
  const unsigned short* qp = Qb + (size_t)(bm * HW2 + qt * 16 + l15) * 64 + lg * 8;
  s16x8 qa0 = *(const s16x8*)qp;
  s16x8 qa1 = *(const s16x8*)(qp + 32);

  // S^T = K Q over this wave's 256 att-cols
  f32x4 acc[16];
  const unsigned short* kbase = Kb + (size_t)bm * HW2 * 64;
  #pragma unroll
  for (int ct = 0; ct < 16; ++ct) {
    int col = wid * 256 + ct * 16 + l15;
    const unsigned short* kp = kbase + (size_t)col * 64 + lg * 8;
    s16x8 kb0 = *(const s16x8*)kp;
    s16x8 kb1 = *(const s16x8*)(kp + 32);
    f32x4 a = (f32x4){0.f, 0.f, 0.f, 0.f};
    a = mfma16(kb0, qa0, a);
    a = mfma16(kb1, qa1, a);
    acc[ct] = a;
  }

  // + pos bias from L1-resident table; per-lane row max.
  // idx(qr,col) = 63*(col>>5) + (col&31) + 1984 - 63*(qr>>5) - (qr&31); qr = qt*16+l15.
  int cb = 1984 - 63 * (qt >> 1) - ((qt & 1) << 4) - l15;
  float pm = -1e30f;
  #pragma unroll
  for (int ct = 0; ct < 16; ++ct) {
    int c0 = wid * 256 + ct * 16 + lg * 4;
    int t0 = 63 * (c0 >> 5) + (c0 & 31) + cb;
    f32x4 pv;
    __builtin_memcpy(&pv, ptab + t0, 16);
    #pragma unroll
    for (int i = 0; i < 4; ++i) {
      float v = acc[ct][i] + pv[i];
      acc[ct][i] = v;
      pm = fmaxf(pm, v);
    }
  }
  pm = fmaxf(pm, __shfl_xor(pm, 16));
  pm = fmaxf(pm, __shfl_xor(pm, 32));
  if (lane < 16) redm[wid][l15] = pm;
  __syncthreads();
  float mrow = fmaxf(fmaxf(redm[0][l15], redm[1][l15]),
                     fmaxf(redm[2][l15], redm[3][l15]));

  // exp + per-lane sum
  float ps = 0.f;
  #pragma unroll
  for (int ct = 0; ct < 16; ++ct) {
    #pragma unroll
    for (int i = 0; i < 4; ++i) {
      float e = __expf(acc[ct][i] - mrow);
      acc[ct][i] = e;
      ps += e;
    }
  }
  ps += __shfl_xor(ps, 16);
  ps += __shfl_xor(ps, 32);
  if (lane < 16) reds[wid][l15] = ps;
  __syncthreads();
  float inv = 1.0f / (reds[0][l15] + reds[1][l15] + reds[2][l15] + reds[3][l15]);

  // att via swizzled LDS staging -> 256B segments; P packed b64.
  float* abase = att + (size_t)(bm * HW2 + qt * 16) * HW2 + wid * 256;
  #pragma unroll
  for (int q = 0; q < 4; ++q) {
    #pragma unroll
    for (int t4 = 0; t4 < 4; ++t4) {
      int ct = q * 4 + t4;
      int c0 = wid * 256 + ct * 16 + lg * 4;
      f32x4 vv;
      #pragma unroll
      for (int i = 0; i < 4; ++i) vv[i] = acc[ct][i] * inv;
      int cw = (t4 * 4 + lg) ^ (l15 & 7);          // 16B-chunk XOR swizzle
      *(f32x4*)&stg[wid][l15][cw * 4] = vv;
      s16x4 pk;
      #pragma unroll
      for (int i = 0; i < 4; ++i) pk[i] = (short)f2b(vv[i]);
      *(s16x4*)&P[l15][c0] = pk;
    }
    __syncthreads();                               // stg writes visible
    #pragma unroll
    for (int i = 0; i < 4; ++i) {
      int r = i * 4 + lg;
      int cr = l15 ^ (r & 7);
      f32x4 vv2 = *(const f32x4*)&stg[wid][r][cr * 4];
      __builtin_nontemporal_store(vv2,
          (f32x4*)(abase + (size_t)r * HW2 + q * 64 + l15 * 4));
    }
    __syncthreads();                               // WAR before next q reuse
  }

  // o = P @ V, swapped: mfma(V, P) -> D[row=dh][col=q-row] -> packed b64 O
  // (last barrier above also covers P completion)
  f32x4 o = (f32x4){0.f, 0.f, 0.f, 0.f};
  const unsigned short* vbase = Vt + (size_t)(bm * 64 + wid * 16 + l15) * HW2;
  #pragma unroll
  for (int kt = 0; kt < 32; ++kt) {
    s16x8 vb = *(const s16x8*)(vbase + kt * 32 + lg * 8);
    s16x8 pa = *(const s16x8*)&P[l15][kt * 32 + lg * 8];
    o = mfma16(vb, pa, o);
  }
  s16x4 ok;
  #pragma unroll
  for (int i = 0; i < 4; ++i) ok[i] = (short)f2b(o[i]);
  *(s16x4*)(O + (size_t)(bm * HW2 + qt * 16 + l15) * 64 + wid * 16 + lg * 4) = ok;
}

// ---------------- head transform: out = gather(O) @ w_ht + b_ht ----------------
__global__ __launch_bounds__(256) void k_ht(
    const unsigned short* __restrict__ O, const unsigned short* __restrict__ WhtT,
    const float* __restrict__ b_ht, float* __restrict__ out) {
  int rt = blockIdx.x >> 1;
  int ch = blockIdx.x & 1;
  int wid = threadIdx.x >> 6, lane = threadIdx.x & 63;
  int wr = wid >> 1, wc = wid & 1;
  int l15 = lane & 15, lg = lane >> 4;
  int b = (rt * 32) >> 10;
  int p0 = (rt * 32) & 1023;

  __shared__ unsigned short A[32][520];   // padded: row stride 1040 B

  int t = threadIdx.x;
  #pragma unroll
  for (int j = 0; j < 8; ++j) {
    int idx = t * 8 + j * 2048;          // [0, 16384)
    int row = idx >> 9;
    int k0 = idx & 511;
    int m = k0 >> 6, kk = k0 & 63;
    const unsigned short* src = O + (size_t)((b * 8 + m) * HW2 + p0 + row) * 64 + kk;
    *(s16x8*)&A[row][k0] = *(const s16x8*)src;
  }
  __syncthreads();

  f32x4 acc[8];
  #pragma unroll
  for (int ct = 0; ct < 8; ++ct) acc[ct] = (f32x4){0.f, 0.f, 0.f, 0.f};

  #pragma unroll
  for (int kt = 0; kt < 16; ++kt) {
    s16x8 a = *(const s16x8*)&A[wr * 16 + l15][kt * 32 + lg * 8];
    #pragma unroll
    for (int ct = 0; ct < 8; ++ct) {
      int col = ch * 256 + wc * 128 + ct * 16 + l15;
      s16x8 bf = *(const s16x8*)(WhtT + (size_t)col * 512 + kt * 32 + lg * 8);
      acc[ct] = mfma16(bf, a, acc[ct]);   // swapped: D[row=col][col=pixel]
    }
  }

  int rp = rt * 32 + wr * 16 + l15;
  #pragma unroll
  for (int ct = 0; ct < 8; ++ct) {
    int c0 = ch * 256 + wc * 128 + ct * 16 + lg * 4;
    f32x4 bb = *(const f32x4*)(b_ht + c0);
    f32x4 ov;
    #pragma unroll
    for (int i = 0; i < 4; ++i) ov[i] = acc[ct][i] + bb[i];
    __builtin_nontemporal_store(ov, (f32x4*)(out + (size_t)rp * 512 + c0));
  }
}

// ---------------- launcher ----------------
extern "C" void kernel_launch(void* const* d_in, const int* in_sizes, int n_in,
                              void* d_out, int out_size, void* d_ws, size_t ws_size,
                              hipStream_t stream) {
  const float* x         = (const float*)d_in[0];
  const float* w_qkv     = (const float*)d_in[1];
  const float* b_qkv     = (const float*)d_in[2];
  const float* w_ht      = (const float*)d_in[3];
  const float* b_ht      = (const float*)d_in[4];
  const float* pos_table = (const float*)d_in[5];
  const int*   pos_idx   = (const int*)d_in[6];

  float* out = (float*)d_out;                  // 4,194,304
  float* att = out + 4194304;                  // 67,108,864
  float* pe  = att + 67108864;                 // 1,048,576

  char* ws = (char*)d_ws;
  unsigned short* Qb   = (unsigned short*)(ws);
  unsigned short* Kb   = (unsigned short*)(ws + (8u  << 20));
  unsigned short* Vt   = (unsigned short*)(ws + (16u << 20));
  unsigned short* O    = (unsigned short*)(ws + (24u << 20));
  unsigned short* Wtq  = (unsigned short*)(ws + (32u << 20));
  unsigned short* Wtk  = Wtq + 4096;
  unsigned short* Wtv  = Wtk + 4096;
  unsigned short* WhtT = (unsigned short*)(ws + (32u << 20) + 65536);

  k_prep<<<2064, 256, 0, stream>>>(w_qkv, w_ht, pos_table, pos_idx,
                                   Wtq, Wtk, Wtv, WhtT, pe);
  k_qkv <<<1024, 256, 0, stream>>>(x, b_qkv, Wtq, Wtk, Wtv, Qb, Kb, Vt);
  k_attn<<<4096, 256, 0, stream>>>(Qb, Kb, Vt, pos_table, att, O);
  k_ht  <<<512,  256, 0, stream>>>(O, WhtT, b_ht, out);
}